// Round 5
// baseline (363.810 us; speedup 1.0000x reference)
//
#include <hip/hip_runtime.h>
#include <math.h>

// Problem constants (GroupedKANLayer): B=2, C=31, D=7, H=W=192
#define NBATCH 2
#define NC 31
#define ND 7
#define NH 192
#define NW 192
#define HW (NH * NW)            // 36864
#define NP (NBATCH * HW)        // 73728 pixels
#define NBASIS 8
#define CLEN 56                 // ND * NBASIS
#define KP 70                   // CLEN + ND + ND

// fused tiling: 64 consecutive pixels of one image row per block
#define FPX 64
#define HCOL 66                 // halo cols (64 + 2)
#define HROW 3                  // halo rows
#define HPLANE (HROW * HCOL)    // 198 words per ic
#define WSTR 73                 // wlds row stride (odd -> 2-way LDS aliasing = free)

// ---------------------------------------------------------------------------
// Kernel 1: ctx[b,c,h,w] = mean_d windowed_x[b,c,d,h,w]
// ---------------------------------------------------------------------------
__global__ __launch_bounds__(256) void ctx_mean_kernel(
    const float* __restrict__ x, float* __restrict__ ctx)
{
    int idx = blockIdx.x * 256 + threadIdx.x;
    if (idx >= NBATCH * NC * HW) return;
    int hw = idx % HW;
    int bc = idx / HW;
    const float* src = x + bc * (ND * HW) + hw;
    float s = 0.f;
#pragma unroll
    for (int d = 0; d < ND; ++d) s += src[d * HW];
    ctx[idx] = s * (1.0f / 7.0f);
}

// ---------------------------------------------------------------------------
// Fused conv + KAN kernel. Block = 256 threads, 64 pixels (one row segment).
// Phase 1: stage 31-channel 3x66 ctx halo into LDS (24.5 KB), one barrier.
// Phase 2: wave w computes oc-group {18,18,17,17} for all 64 pixels.
//          Stencil ds_reads lane-consecutive (conflict-free); weights are
//          wave-uniform s_loads; results go to LDS wlds[64][73] (odd stride).
// Phase 3: wave w evaluates 8 KAN channels/pixel; coef gathered from wlds
//          (stride 73 -> 2-way = free); x loads / out stores coalesced.
// wts NEVER touches global memory.
// grid = NP/64 = 1152 blocks.
// ---------------------------------------------------------------------------
__global__ __launch_bounds__(256, 3) void fused_kernel(
    const float* __restrict__ x, const float* __restrict__ ctx,
    const float* __restrict__ gw, const float* __restrict__ gb,
    float* __restrict__ out)
{
    __shared__ float halo[NC * HPLANE];   // 31*198*4 = 24552 B
    __shared__ float wlds[FPX * WSTR];    // 64*73*4  = 18688 B

    const int tid = threadIdx.x;
    const int px  = tid & 63;
    const int wv  = tid >> 6;

    const int p0 = blockIdx.x * FPX;
    const int b  = p0 / HW;
    const int hw0 = p0 - b * HW;
    const int h  = hw0 / NW;
    const int w0 = hw0 - h * NW;          // 0, 64, or 128

    // ---- Phase 1: stage halo (198 cells per ic; threads 0..197 active) ----
    {
        const float* cb = ctx + (b * NC) * HW;
        if (tid < HPLANE) {
            int r = tid / HCOL;
            int c = tid - r * HCOL;
            int gh = h + r - 1;
            int gc = w0 + c - 1;
            bool ok = (gh >= 0) && (gh < NH) && (gc >= 0) && (gc < NW);
            int ghc = min(max(gh, 0), NH - 1);
            int gcc = min(max(gc, 0), NW - 1);
            int off = ghc * NW + gcc;
            float m = ok ? 1.f : 0.f;
#pragma unroll 4
            for (int ic = 0; ic < NC; ++ic)
                halo[ic * HPLANE + tid] = cb[ic * HW + off] * m;
        }
    }
    __syncthreads();

    // ---- Phase 2: conv. oc-groups {0:18, 18:18, 36:17, 53:17} ----
    {
        const int ob_  = (wv < 2) ? wv * 18 : 36 + (wv - 2) * 17;
        const int ocnt = (wv < 2) ? 18 : 17;

        float acc[18];
        for (int oc = 0; oc < ocnt; ++oc) acc[oc] = gb[ob_ + oc];

        const float* hb = halo + px;
        for (int ic = 0; ic < NC; ++ic) {
            const float* t0 = hb + ic * HPLANE;
            float v00 = t0[0],         v01 = t0[1],         v02 = t0[2];
            float v10 = t0[HCOL],      v11 = t0[HCOL + 1],  v12 = t0[HCOL + 2];
            float v20 = t0[2 * HCOL],  v21 = t0[2 * HCOL + 1], v22 = t0[2 * HCOL + 2];

            const float* wb = gw + (ob_ * NC + ic) * 9;   // wave-uniform
            for (int oc = 0; oc < ocnt; ++oc) {
                const float* w9 = wb + oc * (NC * 9);
                acc[oc] += v00 * w9[0] + v01 * w9[1] + v02 * w9[2]
                         + v10 * w9[3] + v11 * w9[4] + v12 * w9[5]
                         + v20 * w9[6] + v21 * w9[7] + v22 * w9[8];
            }
        }

        float* wr = wlds + px * WSTR + ob_;
        for (int oc = 0; oc < ocnt; ++oc) wr[oc] = acc[oc];
    }
    __syncthreads();

    // ---- Phase 3: KAN. wave wv -> channels [wv*8, min(wv*8+8, 31)) ----
    {
        const float* cbase = wlds + px * WSTR;
        float uw[ND], rw[ND];
#pragma unroll
        for (int d = 0; d < ND; ++d) uw[d] = cbase[CLEN + d];
#pragma unroll
        for (int d = 0; d < ND; ++d) rw[d] = cbase[CLEN + ND + d];

        const float* xb = x + (b * NC) * (ND * HW) + h * NW + w0 + px;
        float* ob = out + (b * NC) * HW + h * NW + w0 + px;

        const int c_begin = wv * 8;
        const int c_end   = (c_begin + 8 < NC) ? c_begin + 8 : NC;

        for (int c = c_begin; c < c_end; ++c) {
            float s = 0.f;
#pragma unroll
            for (int d = 0; d < ND; ++d) {
                float xv = xb[(c * ND + d) * HW];

                // ---- cardinal cubic B-spline (uniform knots) ----
                float t = (xv + 2.2f) * 2.5f;
                float fi = floorf(t);
                int i = (int)fi;
                float u = t - fi;
                float u2 = u * u, u3 = u2 * u;
                float um = 1.f - u;
                float w0_ = um * um * um * (1.f / 6.f);
                float w1_ = (3.f * u3 - 6.f * u2 + 4.f) * (1.f / 6.f);
                float w2_ = (-3.f * u3 + 3.f * u2 + 3.f * u + 1.f) * (1.f / 6.f);
                float w3_ = u3 * (1.f / 6.f);
                int j0 = i - 3;
                float sd = 0.f;
#pragma unroll
                for (int k = 0; k < 4; ++k) {
                    int j = j0 + k;
                    bool valid = (j >= 0) && (j <= 7);
                    int jc = valid ? j : 0;
                    float wk = (k == 0) ? w0_ : (k == 1) ? w1_ : (k == 2) ? w2_ : w3_;
                    float cf = cbase[d * NBASIS + jc];
                    sd += (valid ? wk : 0.f) * cf;
                }
                s += uw[d] * sd;

                // ---- SiLU residual ----
                float sig = 1.f / (1.f + __expf(-xv));
                s += rw[d] * (xv * sig);
            }
            ob[c * HW] = s;
        }
    }
}

// ---------------------------------------------------------------------------
extern "C" void kernel_launch(void* const* d_in, const int* in_sizes, int n_in,
                              void* d_out, int out_size, void* d_ws, size_t ws_size,
                              hipStream_t stream)
{
    const float* x  = (const float*)d_in[0];   // (2,31,7,192,192)
    const float* gw = (const float*)d_in[1];   // (70,31,3,3)
    const float* gb = (const float*)d_in[2];   // (70,)
    float* out = (float*)d_out;                // (2,31,192,192)

    float* ctx = (float*)d_ws;                 // 9.1 MB scratch

    int n1 = NBATCH * NC * HW;
    ctx_mean_kernel<<<dim3((n1 + 255) / 256), 256, 0, stream>>>(x, ctx);
    fused_kernel<<<dim3(NP / FPX), 256, 0, stream>>>(x, ctx, gw, gb, out);
}

// Round 6
// 177.697 us; speedup vs baseline: 2.0474x; 2.0474x over previous
//
#include <hip/hip_runtime.h>
#include <math.h>

// Problem constants (GroupedKANLayer): B=2, C=31, D=7, H=W=192
#define NBATCH 2
#define NC 31
#define ND 7
#define NH 192
#define NW 192
#define HW (NH * NW)            // 36864
#define NP (NBATCH * HW)        // 73728 pixels
#define NBASIS 8
#define CLEN 56                 // ND * NBASIS
#define KP 70                   // CLEN + ND + ND
#define OCB 5                   // output-channel chunk (70 = 14 * 5): 45 weight
                                // SGPRs/ic -> compiler can double-buffer weights

// conv tiling: 32x32 tile, wave-private 8-row strips, no barriers
#define CTS 32
#define WROWS 8                 // tile rows per wave
#define HROWS 10                // halo rows per wave (8 + 2)
#define HCOLS 34                // halo cols
#define WCELLS (HROWS * HCOLS)  // 340 words per wave
#define NSLOT 6                 // ceil(340/64) staging slots per lane

// kan tiling: 64 pixels x 4 channel-groups per block
#define KPPB 64

// ---------------------------------------------------------------------------
// Kernel 1 (v2): ctx = mean_d x, float4-vectorized (16 B/lane).
// ---------------------------------------------------------------------------
__global__ __launch_bounds__(256) void ctx_mean_kernel(
    const float4* __restrict__ x4, float4* __restrict__ ctx4)
{
    const int HW4 = HW / 4;
    int idx = blockIdx.x * 256 + threadIdx.x;      // over NBATCH*NC*HW4
    if (idx >= NBATCH * NC * HW4) return;
    int hw4 = idx % HW4;
    int bc  = idx / HW4;
    const float4* src = x4 + (size_t)bc * (ND * HW4) + hw4;
    float4 a = src[0];
#pragma unroll
    for (int d = 1; d < ND; ++d) {
        float4 v = src[d * HW4];
        a.x += v.x; a.y += v.y; a.z += v.z; a.w += v.w;
    }
    const float inv = 1.0f / 7.0f;
    a.x *= inv; a.y *= inv; a.z *= inv; a.w *= inv;
    ctx4[idx] = a;
}

// ---------------------------------------------------------------------------
// Kernel 2 (v5): 32x32 tile, 5 oc per block (blockIdx.z uniform -> s_loads).
// Wave-private 10x34 halo strips in LDS, zero barriers, register-pipelined
// staging (loads for ic+1 issue before ic's FMAs; ds_writes after).
// grid = (6, 12, 14) = 1008 blocks -> ~4 blocks/CU.
// ---------------------------------------------------------------------------
__global__ __launch_bounds__(256, 4) void conv_kernel(
    const float* __restrict__ ctx, const float* __restrict__ gw,
    const float* __restrict__ gb, float* __restrict__ wts)
{
    __shared__ float tile[4][WCELLS];   // 5440 B

    const int tid  = threadIdx.x;
    const int lane = tid & 63;
    const int wv   = tid >> 6;
    const int tx0  = blockIdx.x * CTS;
    const int by   = blockIdx.y;
    const int b    = by / (NH / CTS);
    const int ty0  = (by - b * (NH / CTS)) * CTS;
    const int oc0  = blockIdx.z * OCB;            // uniform -> weights s_load
    const int wrow0 = wv * WROWS;

    int   off[NSLOT];
    float msk[NSLOT];
    bool  stv[NSLOT];
#pragma unroll
    for (int s = 0; s < NSLOT; ++s) {
        int cell = lane + s * 64;
        int r = cell / HCOLS;
        int c = cell - r * HCOLS;
        int gh = ty0 + wrow0 + r - 1;
        int gc = tx0 + c - 1;
        bool ok = (gh >= 0) && (gh < NH) && (gc >= 0) && (gc < NW);
        int ghc = min(max(gh, 0), NH - 1);
        int gcc = min(max(gc, 0), NW - 1);
        off[s] = ghc * NW + gcc;
        msk[s] = ok ? 1.f : 0.f;
        stv[s] = (cell < WCELLS);
    }

    const float* cb  = ctx + (b * NC) * HW;
    float*       myt = tile[wv];

    {   // prologue: stage ic = 0
        float t[NSLOT];
#pragma unroll
        for (int s = 0; s < NSLOT; ++s) t[s] = cb[off[s]] * msk[s];
#pragma unroll
        for (int s = 0; s < NSLOT; ++s)
            if (stv[s]) myt[lane + s * 64] = t[s];
    }

    float acc[OCB][4];
#pragma unroll
    for (int oc = 0; oc < OCB; ++oc) {
        float bv = gb[oc0 + oc];
#pragma unroll
        for (int k = 0; k < 4; ++k) acc[oc][k] = bv;
    }

    const int strip = lane >> 5;
    const int col   = lane & 31;
    const float* t0 = myt + (strip * 4) * HCOLS + col;

    for (int ic = 0; ic < NC; ++ic) {
        float nxt[NSLOT];
        if (ic + 1 < NC) {
            const float* src = cb + (ic + 1) * HW;
#pragma unroll
            for (int s = 0; s < NSLOT; ++s) nxt[s] = src[off[s]] * msk[s];
        }

        float v[6][3];
#pragma unroll
        for (int j = 0; j < 6; ++j)
#pragma unroll
            for (int c = 0; c < 3; ++c)
                v[j][c] = t0[j * HCOLS + c];

        const float* wb = gw + (oc0 * NC + ic) * 9;
#pragma unroll
        for (int oc = 0; oc < OCB; ++oc) {
            const float* w9 = wb + oc * (NC * 9);
            float w00 = w9[0], w01 = w9[1], w02 = w9[2];
            float w10 = w9[3], w11 = w9[4], w12 = w9[5];
            float w20 = w9[6], w21 = w9[7], w22 = w9[8];
#pragma unroll
            for (int k = 0; k < 4; ++k) {
                acc[oc][k] += v[k][0] * w00 + v[k][1] * w01 + v[k][2] * w02
                            + v[k + 1][0] * w10 + v[k + 1][1] * w11 + v[k + 1][2] * w12
                            + v[k + 2][0] * w20 + v[k + 2][1] * w21 + v[k + 2][2] * w22;
            }
        }

        if (ic + 1 < NC) {
#pragma unroll
            for (int s = 0; s < NSLOT; ++s)
                if (stv[s]) myt[lane + s * 64] = nxt[s];
        }
    }

    const int pbase = b * HW + (ty0 + wrow0 + strip * 4) * NW + (tx0 + col);
#pragma unroll
    for (int oc = 0; oc < OCB; ++oc)
#pragma unroll
        for (int k = 0; k < 4; ++k)
            wts[(oc0 + oc) * NP + pbase + k * NW] = acc[oc][k];
}

// ---------------------------------------------------------------------------
// Kernel 3 (v6): block = 64 pixels, 4 waves, wave wv -> channels
// [wv*8, min(wv*8+8,31)). Grid 1152 blocks -> ~18 waves/CU.
// LDS scoef [k][64]: gather addr = k*64 + pix -> bank = pix%32, worst-case
// 2-way (free). One barrier total.
// ---------------------------------------------------------------------------
__global__ __launch_bounds__(256, 4) void kan_kernel(
    const float* __restrict__ x, const float* __restrict__ wts,
    float* __restrict__ out)
{
    __shared__ float scoef[CLEN * KPPB];   // 56*64*4 = 14336 B
    const int tid = threadIdx.x;
    const int p0  = blockIdx.x * KPPB;

    // stage coef: f = k*64 + pix, 14 fully-coalesced passes
#pragma unroll
    for (int f = tid; f < CLEN * KPPB; f += 256)
        scoef[f] = wts[(f >> 6) * NP + p0 + (f & 63)];

    const int pix = tid & 63;
    const int wv  = tid >> 6;
    const int p   = p0 + pix;

    float uw[ND], rw[ND];
#pragma unroll
    for (int d = 0; d < ND; ++d) uw[d] = wts[(CLEN + d) * NP + p];
#pragma unroll
    for (int d = 0; d < ND; ++d) rw[d] = wts[(CLEN + ND + d) * NP + p];

    __syncthreads();

    const int b  = p / HW;                 // uniform (HW % 64 == 0)
    const int hw = p - b * HW;
    const float* xb = x + (b * NC) * (ND * HW) + hw;
    float* ob = out + (b * NC) * HW + hw;
    const float* cbase = scoef + pix;

    const int c_begin = wv * 8;
    const int c_end   = (c_begin + 8 < NC) ? c_begin + 8 : NC;

    for (int c = c_begin; c < c_end; ++c) {
        float s = 0.f;
#pragma unroll
        for (int d = 0; d < ND; ++d) {
            float xv = xb[(c * ND + d) * HW];

            // ---- cardinal cubic B-spline (uniform knots) ----
            float t = (xv + 2.2f) * 2.5f;
            float fi = floorf(t);
            int i = (int)fi;
            float u = t - fi;
            float u2 = u * u, u3 = u2 * u;
            float um = 1.f - u;
            float w0 = um * um * um * (1.f / 6.f);
            float w1 = (3.f * u3 - 6.f * u2 + 4.f) * (1.f / 6.f);
            float w2 = (-3.f * u3 + 3.f * u2 + 3.f * u + 1.f) * (1.f / 6.f);
            float w3 = u3 * (1.f / 6.f);
            int j0 = i - 3;
            float sd = 0.f;
#pragma unroll
            for (int k = 0; k < 4; ++k) {
                int j = j0 + k;
                bool valid = (j >= 0) && (j <= 7);
                int jc = valid ? j : 0;
                float wk = (k == 0) ? w0 : (k == 1) ? w1 : (k == 2) ? w2 : w3;
                float cf = cbase[(d * NBASIS + jc) * KPPB];
                sd += (valid ? wk : 0.f) * cf;
            }
            s += uw[d] * sd;

            // ---- SiLU residual ----
            float sig = 1.f / (1.f + __expf(-xv));
            s += rw[d] * (xv * sig);
        }
        ob[c * HW] = s;
    }
}

// ---------------------------------------------------------------------------
extern "C" void kernel_launch(void* const* d_in, const int* in_sizes, int n_in,
                              void* d_out, int out_size, void* d_ws, size_t ws_size,
                              hipStream_t stream)
{
    const float* x  = (const float*)d_in[0];   // (2,31,7,192,192)
    const float* gw = (const float*)d_in[1];   // (70,31,3,3)
    const float* gb = (const float*)d_in[2];   // (70,)
    float* out = (float*)d_out;                // (2,31,192,192)

    float* ctx = (float*)d_ws;                       // 9.1 MB
    float* wts = ctx + (size_t)NBATCH * NC * HW;     // 20.6 MB

    int n4 = NBATCH * NC * (HW / 4);
    ctx_mean_kernel<<<dim3((n4 + 255) / 256), 256, 0, stream>>>(
        (const float4*)x, (float4*)ctx);
    conv_kernel<<<dim3(NW / CTS, (NH / CTS) * NBATCH, KP / OCB), 256, 0, stream>>>(ctx, gw, gb, wts);
    kan_kernel<<<dim3(NP / KPPB), 256, 0, stream>>>(x, wts, out);
}

// Round 7
// 169.436 us; speedup vs baseline: 2.1472x; 1.0488x over previous
//
#include <hip/hip_runtime.h>
#include <math.h>

// Problem constants (GroupedKANLayer): B=2, C=31, D=7, H=W=192
#define NBATCH 2
#define NC 31
#define ND 7
#define NH 192
#define NW 192
#define HW (NH * NW)            // 36864
#define NP (NBATCH * HW)        // 73728 pixels
#define NBASIS 8
#define CLEN 56                 // ND * NBASIS
#define KP 70                   // CLEN + ND + ND
#define OCB 5                   // 70 = 14 * 5 -> 45 weight SGPRs/ic

// conv v6 tiling: 32-col x 16-row tile, wave-private 4-row strips, no barriers
#define CTSX 32
#define CTSY 16
#define WROWS 4                 // tile rows per wave
#define HROWS 6                 // halo rows per wave (4 + 2)
#define HCOLS 34                // halo cols
#define WCELLS (HROWS * HCOLS)  // 204 words per wave
#define NSLOT 4                 // ceil(204/64) staging slots per lane

// kan tiling: 64 pixels per block, channel-pair ILP
#define KPPB 64

// ---------------------------------------------------------------------------
// Kernel 1: ctx = mean_d x, float4-vectorized (16 B/lane).
// ---------------------------------------------------------------------------
__global__ __launch_bounds__(256) void ctx_mean_kernel(
    const float4* __restrict__ x4, float4* __restrict__ ctx4)
{
    const int HW4 = HW / 4;
    int idx = blockIdx.x * 256 + threadIdx.x;      // over NBATCH*NC*HW4
    if (idx >= NBATCH * NC * HW4) return;
    int hw4 = idx % HW4;
    int bc  = idx / HW4;
    const float4* src = x4 + (size_t)bc * (ND * HW4) + hw4;
    float4 a = src[0];
#pragma unroll
    for (int d = 1; d < ND; ++d) {
        float4 v = src[d * HW4];
        a.x += v.x; a.y += v.y; a.z += v.z; a.w += v.w;
    }
    const float inv = 1.0f / 7.0f;
    a.x *= inv; a.y *= inv; a.z *= inv; a.w *= inv;
    ctx4[idx] = a;
}

// ---------------------------------------------------------------------------
// Kernel 2 (v6): 32x16 tile, 5 oc per block (blockIdx.z uniform -> s_loads).
// Wave-private 6x34 halo strips in LDS, zero barriers, register-pipelined
// staging. Each thread: 2 pixel rows x 5 oc -> 90 FMA / 12 ds_reads per ic.
// grid = (6, 24, 14) = 2016 blocks -> ~7.9 blocks/CU.
// ---------------------------------------------------------------------------
__global__ __launch_bounds__(256, 4) void conv_kernel(
    const float* __restrict__ ctx, const float* __restrict__ gw,
    const float* __restrict__ gb, float* __restrict__ wts)
{
    __shared__ float tile[4][WCELLS];   // 4*204*4 = 3264 B

    const int tid  = threadIdx.x;
    const int lane = tid & 63;
    const int wv   = tid >> 6;
    const int tx0  = blockIdx.x * CTSX;
    const int by   = blockIdx.y;
    const int b    = by / (NH / CTSY);
    const int ty0  = (by - b * (NH / CTSY)) * CTSY;
    const int oc0  = blockIdx.z * OCB;            // uniform -> weights s_load
    const int wrow0 = wv * WROWS;

    int   off[NSLOT];
    float msk[NSLOT];
    bool  stv[NSLOT];
#pragma unroll
    for (int s = 0; s < NSLOT; ++s) {
        int cell = lane + s * 64;
        int r = cell / HCOLS;
        int c = cell - r * HCOLS;
        int gh = ty0 + wrow0 + r - 1;
        int gc = tx0 + c - 1;
        bool ok = (gh >= 0) && (gh < NH) && (gc >= 0) && (gc < NW);
        int ghc = min(max(gh, 0), NH - 1);
        int gcc = min(max(gc, 0), NW - 1);
        off[s] = ghc * NW + gcc;
        msk[s] = ok ? 1.f : 0.f;
        stv[s] = (cell < WCELLS);
    }

    const float* cb  = ctx + (b * NC) * HW;
    float*       myt = tile[wv];

    {   // prologue: stage ic = 0
        float t[NSLOT];
#pragma unroll
        for (int s = 0; s < NSLOT; ++s) t[s] = cb[off[s]] * msk[s];
#pragma unroll
        for (int s = 0; s < NSLOT; ++s)
            if (stv[s]) myt[lane + s * 64] = t[s];
    }

    float acc[OCB][2];
#pragma unroll
    for (int oc = 0; oc < OCB; ++oc) {
        float bv = gb[oc0 + oc];
#pragma unroll
        for (int k = 0; k < 2; ++k) acc[oc][k] = bv;
    }

    const int strip = lane >> 5;        // 0/1 -> rows strip*2, strip*2+1
    const int col   = lane & 31;
    const float* t0 = myt + (strip * 2) * HCOLS + col;

    for (int ic = 0; ic < NC; ++ic) {
        float nxt[NSLOT];
        if (ic + 1 < NC) {
            const float* src = cb + (ic + 1) * HW;
#pragma unroll
            for (int s = 0; s < NSLOT; ++s) nxt[s] = src[off[s]] * msk[s];
        }

        float v[4][3];
#pragma unroll
        for (int j = 0; j < 4; ++j)
#pragma unroll
            for (int c = 0; c < 3; ++c)
                v[j][c] = t0[j * HCOLS + c];

        const float* wb = gw + (oc0 * NC + ic) * 9;
#pragma unroll
        for (int oc = 0; oc < OCB; ++oc) {
            const float* w9 = wb + oc * (NC * 9);
            float w00 = w9[0], w01 = w9[1], w02 = w9[2];
            float w10 = w9[3], w11 = w9[4], w12 = w9[5];
            float w20 = w9[6], w21 = w9[7], w22 = w9[8];
#pragma unroll
            for (int k = 0; k < 2; ++k) {
                acc[oc][k] += v[k][0] * w00 + v[k][1] * w01 + v[k][2] * w02
                            + v[k + 1][0] * w10 + v[k + 1][1] * w11 + v[k + 1][2] * w12
                            + v[k + 2][0] * w20 + v[k + 2][1] * w21 + v[k + 2][2] * w22;
            }
        }

        if (ic + 1 < NC) {
#pragma unroll
            for (int s = 0; s < NSLOT; ++s)
                if (stv[s]) myt[lane + s * 64] = nxt[s];
        }
    }

    const int pbase = b * HW + (ty0 + wrow0 + strip * 2) * NW + (tx0 + col);
#pragma unroll
    for (int oc = 0; oc < OCB; ++oc)
#pragma unroll
        for (int k = 0; k < 2; ++k)
            wts[(oc0 + oc) * NP + pbase + k * NW] = acc[oc][k];
}

// ---------------------------------------------------------------------------
// kan helpers
// ---------------------------------------------------------------------------
__device__ __forceinline__ float spline_part(float xv, const float* cb, int d)
{
    // cardinal cubic B-spline on uniform knots; cb = scoef + lane,
    // coef gather at LDS stride 64 words (bank = lane%32, 2-way = free)
    float t = (xv + 2.2f) * 2.5f;
    float fi = floorf(t);
    int i = (int)fi;
    float u = t - fi;
    float u2 = u * u, u3 = u2 * u;
    float um = 1.f - u;
    float w0 = um * um * um * (1.f / 6.f);
    float w3 = u3 * (1.f / 6.f);
    float w1 = (3.f * u3 - 6.f * u2 + 4.f) * (1.f / 6.f);
    float w2 = 1.f - w0 - w1 - w3;          // partition of unity
    int j0 = i - 3;
    float sd = 0.f;
#pragma unroll
    for (int k = 0; k < 4; ++k) {
        int j = j0 + k;
        bool valid = (j >= 0) && (j <= 7);
        int jc = valid ? j : 0;
        float wk = (k == 0) ? w0 : (k == 1) ? w1 : (k == 2) ? w2 : w3;
        float cf = cb[(d * NBASIS + jc) * KPPB];
        sd += (valid ? wk : 0.f) * cf;
    }
    return sd;
}

__device__ __forceinline__ float silu(float xv)
{
    return xv / (1.f + __expf(-xv));
}

// ---------------------------------------------------------------------------
// Kernel 3 (v7): block = 64 pixels, 4 waves. All 70 wts values staged to LDS
// [k][64] (17.9 KB). Wave wv processes 8 channels as 4 PAIRS -> two
// independent spline chains per d (14 x-loads in flight). Wave 3 covers
// channels 23..30; ch 23 is computed identically by waves 2 and 3 (benign).
// grid = 1152 blocks -> 4.5 blocks/CU, 18 waves/CU.
// ---------------------------------------------------------------------------
__global__ __launch_bounds__(256, 3) void kan_kernel(
    const float* __restrict__ x, const float* __restrict__ wts,
    float* __restrict__ out)
{
    __shared__ float scoef[KP * KPPB];   // 70*64*4 = 17920 B
    const int tid = threadIdx.x;
    const int p0  = blockIdx.x * KPPB;

    // stage all 70 wts rows: f = k*64 + pix, fully coalesced
    for (int f = tid; f < KP * KPPB; f += 256)
        scoef[f] = wts[(f >> 6) * NP + p0 + (f & 63)];

    __syncthreads();

    const int lane = tid & 63;
    const int wv   = tid >> 6;
    const int p    = p0 + lane;
    const int b    = p / HW;              // uniform (HW % 64 == 0)
    const int hw   = p - b * HW;

    const float* cb64 = scoef + lane;

    float uw[ND], rw[ND];
#pragma unroll
    for (int d = 0; d < ND; ++d) uw[d] = cb64[(CLEN + d) * KPPB];
#pragma unroll
    for (int d = 0; d < ND; ++d) rw[d] = cb64[(CLEN + ND + d) * KPPB];

    const float* xb = x + (size_t)(b * NC) * (ND * HW) + hw;
    float* ob = out + (b * NC) * HW + hw;

    const int c_begin = (wv == 3) ? 23 : wv * 8;   // 8 channels per wave

#pragma unroll
    for (int i = 0; i < 4; ++i) {
        const int c0 = c_begin + 2 * i;
        const int c1 = c0 + 1;
        const float* x0 = xb + (size_t)c0 * ND * HW;
        const float* x1 = xb + (size_t)c1 * ND * HW;
        float s0 = 0.f, s1 = 0.f;
#pragma unroll
        for (int d = 0; d < ND; ++d) {
            float xv0 = x0[d * HW];
            float xv1 = x1[d * HW];
            s0 += uw[d] * spline_part(xv0, cb64, d) + rw[d] * silu(xv0);
            s1 += uw[d] * spline_part(xv1, cb64, d) + rw[d] * silu(xv1);
        }
        ob[c0 * HW] = s0;
        ob[c1 * HW] = s1;
    }
}

// ---------------------------------------------------------------------------
extern "C" void kernel_launch(void* const* d_in, const int* in_sizes, int n_in,
                              void* d_out, int out_size, void* d_ws, size_t ws_size,
                              hipStream_t stream)
{
    const float* x  = (const float*)d_in[0];   // (2,31,7,192,192)
    const float* gw = (const float*)d_in[1];   // (70,31,3,3)
    const float* gb = (const float*)d_in[2];   // (70,)
    float* out = (float*)d_out;                // (2,31,192,192)

    float* ctx = (float*)d_ws;                       // 9.1 MB
    float* wts = ctx + (size_t)NBATCH * NC * HW;     // 20.6 MB

    int n4 = NBATCH * NC * (HW / 4);
    ctx_mean_kernel<<<dim3((n4 + 255) / 256), 256, 0, stream>>>(
        (const float4*)x, (float4*)ctx);
    conv_kernel<<<dim3(NW / CTSX, (NH / CTSY) * NBATCH, KP / OCB), 256, 0, stream>>>(ctx, gw, gb, wts);
    kan_kernel<<<dim3(NP / KPPB), 256, 0, stream>>>(x, wts, out);
}